// Round 16
// baseline (141.941 us; speedup 1.0000x reference)
//
#include <hip/hip_runtime.h>
#include <hip/hip_fp16.h>
#include <math.h>

#define NI   32
#define NH   1024
#define NB   1024

// ws layout. g-axis (h2) degree-SORTED; h1-axis natural. W2/W1 stored as F16.
//   fp32: b1s[1056] @0, b2s[1024] @1056, W3s[64][1024] @2080
//   W1B  (uint)  @67616 : W1B[k][su] = f16(W1m[j=2k][su]) | f16(W1m[2k+1][su])<<16
//   PB   (uint4) @84512 : panel dd, pair u2, sg-quad Q; each uint packs the
//                         (u even, u odd) k-pair for one sg unit (dot2-ready)
#define OFF_B1S 0
#define OFF_B2S 1056
#define OFF_W3S 2080
#define OFF_W1B 67616            // float-index (4B units)
#define OFF_PB  84512            // float-index; PB block idx = (dd*17+u2)*256 + Q

__device__ __forceinline__ int base_of(int d) { return (d == 0) ? 0 : 33 * d + 1; }

__device__ __forceinline__ unsigned short f2h(float f) {   // RNE f32->f16
    return __half_as_ushort(__float2half(f));
}

typedef _Float16 h2v __attribute__((ext_vector_type(2)));
__device__ __forceinline__ h2v as_h2(unsigned u) {
    union { unsigned u; h2v h; } c; c.u = u; return c.h;
}
// acc += a.h0*b.h0 + a.h1*b.h1  (exact f16 products, f32 accumulate)
__device__ __forceinline__ float fdot2u(unsigned a, unsigned b, float c) {
#if __has_builtin(__builtin_amdgcn_fdot2)
    return __builtin_amdgcn_fdot2(as_h2(a), as_h2(b), c, false);
#else
    h2v ah = as_h2(a), bh = as_h2(b);
    return fmaf((float)ah.x, (float)bh.x, fmaf((float)ah.y, (float)bh.y, c));
#endif
}

// ---- fast wave-wide sum: DPP for xor1/2/4/8, permlane-swap for 16/32 ----
template <int CTRL>
__device__ __forceinline__ float dpp_add(float s) {
    int t = __builtin_amdgcn_update_dpp(0, __float_as_int(s), CTRL, 0xF, 0xF, true);
    return s + __int_as_float(t);
}

__device__ __forceinline__ float wave_allsum(float s) {
    s = dpp_add<0xB1>(s);    // quad_perm [1,0,3,2] : + s[lane^1]
    s = dpp_add<0x4E>(s);    // quad_perm [2,3,0,1] : + s[lane^2]
    s = dpp_add<0x141>(s);   // row_half_mirror     : + partner quad in 8
    s = dpp_add<0x140>(s);   // row_mirror          : + partner 8 in 16
#if __has_builtin(__builtin_amdgcn_permlane16_swap)
    {
        using uint2v = __attribute__((ext_vector_type(2))) unsigned int;
        uint2v r = __builtin_amdgcn_permlane16_swap(
            __float_as_uint(s), __float_as_uint(s), false, false);
        s = __uint_as_float(r.x) + __uint_as_float(r.y);
    }
#else
    s += __int_as_float(__builtin_amdgcn_ds_swizzle(__float_as_int(s), 0x401F));
#endif
#if __has_builtin(__builtin_amdgcn_permlane32_swap)
    {
        using uint2v = __attribute__((ext_vector_type(2))) unsigned int;
        uint2v r = __builtin_amdgcn_permlane32_swap(
            __float_as_uint(s), __float_as_uint(s), false, false);
        s = __uint_as_float(r.x) + __uint_as_float(r.y);
    }
#else
    s += __shfl_xor(s, 32, 64);
#endif
    return s;
}

// ---- prep (R26 version: coalesced 62-col W2 pass; og-major small prep) ----
template <int CNT>
__device__ __forceinline__ void prep_w2_cls(int d, int b, const float* __restrict__ W2,
                                            unsigned* __restrict__ pb32, int t,
                                            float (*tile)[63]) {
    const int bse  = base_of(d);
    const int col0 = 62 * b;
    const int ncol = (col0 + 62 <= NH) ? 62 : (NH - col0);   // 32 for b=16
#pragma unroll 1
    for (int e = t; e < CNT * 62; e += 256) {
        int k = e / 62, c = e - 62 * k;
        if (c < ncol) tile[k][c] = W2[(size_t)(d + 31 * k) * NH + col0 + c];
    }
    __syncthreads();
#pragma unroll 1
    for (int e = t; e < 31 * CNT; e += 256) {
        int dd = e / CNT, k = e - CNT * dd;
        int sg = bse + k;
        float lo = (d >= dd) ? tile[k][dd] : 0.0f;            // u = 2b
        float hi = 0.0f;                                       // u = 2b+1
        if (d >= dd && (col0 + dd + 31) < NH) hi = tile[k][dd + 31];
        unsigned pk = (unsigned)f2h(lo) | ((unsigned)f2h(hi) << 16);
        pb32[(size_t)((dd * 17 + b) * 256 + (sg >> 2)) * 4 + (sg & 3)] = pk;
    }
}

__global__ __launch_bounds__(256) void prep_all(const float* __restrict__ W1,
        const float* __restrict__ b1, const float* __restrict__ W2,
        const float* __restrict__ b2, const float* __restrict__ W3,
        float* __restrict__ ws) {
    __shared__ float tile[34][63];
    const int bid = blockIdx.x, t = threadIdx.x;
    unsigned* pb32 = (unsigned*)(ws + OFF_PB);
    if (bid < 527) {
        int d = bid / 17, b = bid - 17 * d;
        if (d == 0) prep_w2_cls<34>(0, b, W2, pb32, t, tile);
        else        prep_w2_cls<33>(d, b, W2, pb32, t, tile);
    } else if (bid < 591) {
        // W3s row o: coalesced read of W3[o][*], scatter-store to su.
        const int o  = bid - 527;
        const int od = (o & 31) - 1;
#pragma unroll 1
        for (int e = t; e < NH; e += 256) {       // e = og
            int dd = e % 31;
            int k  = e / 31;
            int su = (dd == 0) ? k : 33 * dd + 1 + k;
            float v = (od >= dd) ? W3[(size_t)o * NH + e] : 0.0f;
            ws[OFF_W3S + (size_t)o * NH + su] = v;
        }
    } else {
        // W1B + b1s + b2s: one thread per og; contiguous 128B W1 row/lane.
        const int og = (bid - 591) * 256 + t;
        const int dd = og % 31;
        const int k  = og / 31;
        const int su = (dd == 0) ? k : 33 * dd + 1 + k;
        ws[OFF_B1S + su] = b1[og];
        ws[OFF_B2S + su] = b2[og];
        unsigned* w1b32 = (unsigned*)(ws + OFF_W1B);
        const float4* wrow = (const float4*)(W1 + (size_t)og * NI);
        float4 r[8];
#pragma unroll
        for (int q4 = 0; q4 < 8; ++q4) r[q4] = wrow[q4];
        const float* rf = (const float*)&r[0];
#pragma unroll
        for (int jp = 0; jp < 16; ++jp) {
            float v0 = (dd >= 2 * jp)     ? rf[2 * jp]     : 0.0f;
            float v1 = (dd >= 2 * jp + 1) ? rf[2 * jp + 1] : 0.0f;
            unsigned pk = (unsigned)f2h(v0) | ((unsigned)f2h(v1) << 16);
            w1b32[(size_t)jp * 1056 + su] = pk;
        }
    }
}

// consume one f16 pair-load with dot2: g.{x,y,z,w} = k-pair for unit sg0..3;
// av.x = packed (a0[2u2],a0[2u2+1]), av.y = same for row 1.
__device__ __forceinline__ void consume_pair(uint4 g, uint2 av,
                                             float4& acc0, float4& acc1) {
    acc0.x = fdot2u(av.x, g.x, acc0.x);
    acc0.y = fdot2u(av.x, g.y, acc0.y);
    acc0.z = fdot2u(av.x, g.z, acc0.z);
    acc0.w = fdot2u(av.x, g.w, acc0.w);
    acc1.x = fdot2u(av.y, g.x, acc1.x);
    acc1.y = fdot2u(av.y, g.y, acc1.y);
    acc1.z = fdot2u(av.y, g.z, acc1.z);
    acc1.w = fdot2u(av.y, g.w, acc1.w);
}

// Phase A with NG tap-groups (group q4 covers taps 8q4..8q4+7). Called with
// ng = ceil(i/8): taps j>=i have exactly-zero weights AND xsH[j]=0, so
// skipped groups contribute exact zeros — bit-identical result.
template <int NG>
__device__ __forceinline__ void phase_a(const unsigned* __restrict__ W1Bsu,
        float bz, const unsigned* __restrict__ xh0,
        const unsigned* __restrict__ xh1, float& a0, float& a1) {
    unsigned wk[4 * NG];
#pragma unroll
    for (int k = 0; k < 4 * NG; ++k) wk[k] = W1Bsu[k * 1056];
    float zA0 = bz, zA1 = 0, zA2 = 0, zA3 = 0;
    float zB0 = bz, zB1 = 0, zB2 = 0, zB3 = 0;
#pragma unroll
    for (int q4 = 0; q4 < NG; ++q4) {
        uint4 xp0 = *(const uint4*)(xh0 + 4 * q4);
        uint4 xp1 = *(const uint4*)(xh1 + 4 * q4);
        zA0 = fdot2u(xp0.x, wk[4 * q4 + 0], zA0);
        zB0 = fdot2u(xp1.x, wk[4 * q4 + 0], zB0);
        zA1 = fdot2u(xp0.y, wk[4 * q4 + 1], zA1);
        zB1 = fdot2u(xp1.y, wk[4 * q4 + 1], zB1);
        zA2 = fdot2u(xp0.z, wk[4 * q4 + 2], zA2);
        zB2 = fdot2u(xp1.z, wk[4 * q4 + 2], zB2);
        zA3 = fdot2u(xp0.w, wk[4 * q4 + 3], zA3);
        zB3 = fdot2u(xp1.w, wk[4 * q4 + 3], zB3);
    }
    a0 = fmaxf((zA0 + zA1) + (zA2 + zA3), 0.f);
    a1 = fmaxf((zB0 + zB1) + (zB2 + zB3), 0.f);
}

// R29 = R27 base (71.9us session best; R28's wk prefetch reverted — it was
// TLP-covered already) + zero-quad skip in consume. Panel dd stores EXACT
// ZEROS for all h2 quads Q < goff>>2 (deg < dd). L2 arithmetic: consume
// reads ~685 MB of panel over the dispatch (~20us at L2 ceiling); ~19% of
// it is the partial wave's zero region. The fully-active wave (gb>=goff,
// wave-uniform) keeps R27's exact path; the one partial wave/step takes a
// lane-masked path (exec-masked loads DO suppress L2 traffic). Skipped
// terms are stored zeros -> bit-identical numerics. This also isolates the
// L2-BW hypothesis: null => plateau is issue/latency-structural.
__global__ __launch_bounds__(256, 2) void made_scan(
        const float* __restrict__ inputs,
        const float* __restrict__ b3,
        const float* __restrict__ ws,
        float* __restrict__ out) {
    __shared__ float    xsS[4][2][36];  // per-wave private x, f32 (output path)
    __shared__ unsigned xsH[4][2][20];  // per-wave x as packed f16 pairs
    __shared__ unsigned a1H[4][36];     // per-wave a pairs: [u2*2]=row0, [u2*2+1]=row1
    __shared__ float part[2][4][4];
    __shared__ float b3S[64];
    __shared__ float xinS[2][NI];

    const int lane = threadIdx.x & 63;
    const int w    = threadIdx.x >> 6;
    const int pairity = ((blockIdx.x >> 8) ^ blockIdx.x) & 1;
    const int q    = w ^ (pairity * 3);
    const int gb   = q * 256;
    const int row0 = blockIdx.x * 2;

    const float* b1s = ws + OFF_B1S;
    const float* b2s = ws + OFF_B2S;
    const float* W3s = ws + OFF_W3S;
    const unsigned* W1B = (const unsigned*)(ws + OFF_W1B);
    const uint4*    PB  = (const uint4*)(ws + OFF_PB);

    float4 acc0 = ((const float4*)(b2s + gb))[lane];
    float4 acc1 = acc0;
    float J0 = 0.f, J1 = 0.f;

    if (w == 0) {
        b3S[lane] = b3[lane];
        if (lane < NI) {
            xinS[0][lane] = inputs[row0 * NI + lane];
            xinS[1][lane] = inputs[(row0 + 1) * NI + lane];
        }
    }
    {
        float* px = &xsS[w][0][0];
        for (int k = lane; k < 72; k += 64) px[k] = 0.f;
        unsigned* ph = &xsH[w][0][0];
        for (int k = lane; k < 40; k += 64) ph[k] = 0u;
    }
    __syncthreads();

    // step 0: W3 rows 0/32 fully masked -> p = (b3[0], b3[32])
    {
        float p00 = b3S[0], p01 = b3S[NI];
        float e20 = __expf(2.f * fminf(p01, 15.f));
        float ta  = (e20 - 1.f) / (e20 + 1.f);
        float es  = __expf(ta);
        float x0  = fmaf(xinS[0][0], es, p00);
        float x1  = fmaf(xinS[1][0], es, p00);
        J0 -= ta; J1 -= ta;
        if (lane == 0) {
            xsS[w][0][0] = x0; xsS[w][1][0] = x1;
            ((unsigned short*)&xsH[w][0][0])[0] = f2h(x0);
            ((unsigned short*)&xsH[w][1][0])[0] = f2h(x1);
        }
    }

#pragma unroll 1
    for (int i = 1; i < NI; ++i) {
        const int dd   = i - 1;
        const int goff = base_of(dd);
        const int cnt  = (i == 1) ? 34 : 33;
        const bool doB = (gb + 256 > goff);
        const bool doC = (gb < 33 * i + 1);

        float4 wa = make_float4(0, 0, 0, 0), wb = make_float4(0, 0, 0, 0);
        if (doC) {
            wa = ((const float4*)(W3s + (size_t)i * NH + gb))[lane];
            wb = ((const float4*)(W3s + (size_t)(NI + i) * NH + gb))[lane];
        }

        if (doB) {
            const uint4* pbase = PB + (size_t)(dd * 17) * 256 + (gb >> 2) + lane;
            const int goffq = goff >> 2;          // first quad with nonzeros
            const bool wfull = (gb >> 2) >= goffq; // wave-uniform: all lanes live

            uint4 G[17];
            if (wfull) {                           // R27 path: loads pre-PhaseA
#pragma unroll
                for (int u2 = 0; u2 < 17; ++u2) G[u2] = pbase[u2 * 256];
            }

            // Phase A (all lanes of every doB wave; truncated batched arms)
            const int su = goff + lane;
            float bz = b1s[su];
            const unsigned* xh0 = &xsH[w][0][0];
            const unsigned* xh1 = &xsH[w][1][0];
            const unsigned* W1Bsu = W1B + su;
            float a0, a1;
            const int ng = (i + 7) >> 3;           // ceil(i/8)
            if      (ng == 1) phase_a<1>(W1Bsu, bz, xh0, xh1, a0, a1);
            else if (ng == 2) phase_a<2>(W1Bsu, bz, xh0, xh1, a0, a1);
            else if (ng == 3) phase_a<3>(W1Bsu, bz, xh0, xh1, a0, a1);
            else              phase_a<4>(W1Bsu, bz, xh0, xh1, a0, a1);
            const bool ok = lane < cnt;
            a0 = ok ? a0 : 0.f;
            a1 = ok ? a1 : 0.f;
            if (lane < 36) {                 // publish packed f16 pairs
                unsigned short* ah = (unsigned short*)&a1H[w][0];
                int u2 = lane >> 1, h = lane & 1;
                ah[u2 * 4 + h]     = f2h(a0);
                ah[u2 * 4 + 2 + h] = f2h(a1);
            }

            if (wfull) {
#pragma unroll
                for (int u2 = 0; u2 < 17; ++u2)
                    consume_pair(G[u2], *(const uint2*)&a1H[w][2 * u2], acc0, acc1);
            } else if (((gb >> 2) + lane) >= goffq) {
                // partial wave: lanes below goffq own all-zero quads — skip
                // their loads (saves L2 traffic) and FMAs (exact zeros).
#pragma unroll
                for (int u2 = 0; u2 < 17; ++u2) G[u2] = pbase[u2 * 256];
#pragma unroll
                for (int u2 = 0; u2 < 17; ++u2)
                    consume_pair(G[u2], *(const uint2*)&a1H[w][2 * u2], acc0, acc1);
            }
        }

        // Phase C (fp32 W3; zeros beyond prefix keep it exact)
        float s00 = 0, s01 = 0, s10 = 0, s11 = 0;
        if (doC) {
            float hx, hy, hz, hw;
            hx = fmaxf(acc0.x, 0.f); hy = fmaxf(acc0.y, 0.f);
            hz = fmaxf(acc0.z, 0.f); hw = fmaxf(acc0.w, 0.f);
            s00 = fmaf(wa.x, hx, fmaf(wa.y, hy, fmaf(wa.z, hz, wa.w * hw)));
            s01 = fmaf(wb.x, hx, fmaf(wb.y, hy, fmaf(wb.z, hz, wb.w * hw)));
            hx = fmaxf(acc1.x, 0.f); hy = fmaxf(acc1.y, 0.f);
            hz = fmaxf(acc1.z, 0.f); hw = fmaxf(acc1.w, 0.f);
            s10 = fmaf(wa.x, hx, fmaf(wa.y, hy, fmaf(wa.z, hz, wa.w * hw)));
            s11 = fmaf(wb.x, hx, fmaf(wb.y, hy, fmaf(wb.z, hz, wb.w * hw)));
            s00 = wave_allsum(s00); s01 = wave_allsum(s01);
            s10 = wave_allsum(s10); s11 = wave_allsum(s11);
        }
        if (lane == 0)
            *((float4*)&part[i & 1][w][0]) = make_float4(s00, s01, s10, s11);
        __syncthreads();

        // combine — replicated in every wave; x published to own-wave xs only
        const float* pb = &part[i & 1][0][0];
        float4 q0 = ((const float4*)pb)[0], q1 = ((const float4*)pb)[1];
        float4 q2 = ((const float4*)pb)[2], q3 = ((const float4*)pb)[3];
        float bi  = b3S[i];
        float bia = b3S[NI + i];
        float p00 = ((q0.x + q1.x) + (q2.x + q3.x)) + bi;
        float p01 = ((q0.y + q1.y) + (q2.y + q3.y)) + bia;
        float p10 = ((q0.z + q1.z) + (q2.z + q3.z)) + bi;
        float p11 = ((q0.w + q1.w) + (q2.w + q3.w)) + bia;
        float e20 = __expf(2.f * fminf(p01, 15.f));
        float ta0 = (e20 - 1.f) / (e20 + 1.f);
        float x0  = fmaf(xinS[0][i], __expf(ta0), p00);
        float e21 = __expf(2.f * fminf(p11, 15.f));
        float ta1 = (e21 - 1.f) / (e21 + 1.f);
        float x1  = fmaf(xinS[1][i], __expf(ta1), p10);
        J0 -= ta0; J1 -= ta1;
        if (lane == 0) {
            xsS[w][0][i] = x0; xsS[w][1][i] = x1;
            ((unsigned short*)&xsH[w][0][0])[i] = f2h(x0);
            ((unsigned short*)&xsH[w][1][0])[i] = f2h(x1);
        }
    }

    if (w == 0) {
        if (lane < NI) {
            out[row0 * NI + lane]       = xsS[0][0][lane];
            out[(row0 + 1) * NI + lane] = xsS[0][1][lane];
        }
        if (lane == 0) {
            out[NB * NI + row0]     = J0;
            out[NB * NI + row0 + 1] = J1;
        }
    }
}

extern "C" void kernel_launch(void* const* d_in, const int* in_sizes, int n_in,
                              void* d_out, int out_size, void* d_ws, size_t ws_size,
                              hipStream_t stream) {
    const float* inputs = (const float*)d_in[0];
    const float* W1     = (const float*)d_in[1];
    const float* b1     = (const float*)d_in[2];
    const float* W2     = (const float*)d_in[3];
    const float* b2     = (const float*)d_in[4];
    const float* W3     = (const float*)d_in[5];
    const float* b3     = (const float*)d_in[6];
    float* out = (float*)d_out;
    float* ws  = (float*)d_ws;

    prep_all<<<595, 256, 0, stream>>>(W1, b1, W2, b2, W3, ws);
    made_scan<<<NB / 2, 256, 0, stream>>>(inputs, b3, ws, out);
}

// Round 17
// 138.837 us; speedup vs baseline: 1.0224x; 1.0224x over previous
//
#include <hip/hip_runtime.h>
#include <hip/hip_fp16.h>
#include <math.h>

#define NI   32
#define NH   1024
#define NB   1024

// ws layout. g-axis (h2) degree-SORTED; h1-axis natural. W2/W1 stored as F16.
//   fp32: b1s[1056] @0, b2s[1024] @1056, W3s[64][1024] @2080
//   W1B  (uint)  @67616 : W1B[k][su] = f16(W1m[j=2k][su]) | f16(W1m[2k+1][su])<<16
//   PB   (uint4) @84512 : panel dd, pair u2, sg-quad Q; each uint packs the
//                         (u even, u odd) k-pair for one sg unit (dot2-ready)
#define OFF_B1S 0
#define OFF_B2S 1056
#define OFF_W3S 2080
#define OFF_W1B 67616            // float-index (4B units)
#define OFF_PB  84512            // float-index; PB block idx = (dd*17+u2)*256 + Q

__device__ __forceinline__ int base_of(int d) { return (d == 0) ? 0 : 33 * d + 1; }

__device__ __forceinline__ unsigned short f2h(float f) {   // RNE f32->f16
    return __half_as_ushort(__float2half(f));
}

typedef _Float16 h2v __attribute__((ext_vector_type(2)));
__device__ __forceinline__ h2v as_h2(unsigned u) {
    union { unsigned u; h2v h; } c; c.u = u; return c.h;
}
// acc += a.h0*b.h0 + a.h1*b.h1  (exact f16 products, f32 accumulate)
__device__ __forceinline__ float fdot2u(unsigned a, unsigned b, float c) {
#if __has_builtin(__builtin_amdgcn_fdot2)
    return __builtin_amdgcn_fdot2(as_h2(a), as_h2(b), c, false);
#else
    h2v ah = as_h2(a), bh = as_h2(b);
    return fmaf((float)ah.x, (float)bh.x, fmaf((float)ah.y, (float)bh.y, c));
#endif
}

// ---- fast wave-wide sum: DPP for xor1/2/4/8, permlane-swap for 16/32 ----
template <int CTRL>
__device__ __forceinline__ float dpp_add(float s) {
    int t = __builtin_amdgcn_update_dpp(0, __float_as_int(s), CTRL, 0xF, 0xF, true);
    return s + __int_as_float(t);
}

__device__ __forceinline__ float wave_allsum(float s) {
    s = dpp_add<0xB1>(s);    // quad_perm [1,0,3,2] : + s[lane^1]
    s = dpp_add<0x4E>(s);    // quad_perm [2,3,0,1] : + s[lane^2]
    s = dpp_add<0x141>(s);   // row_half_mirror     : + partner quad in 8
    s = dpp_add<0x140>(s);   // row_mirror          : + partner 8 in 16
#if __has_builtin(__builtin_amdgcn_permlane16_swap)
    {
        using uint2v = __attribute__((ext_vector_type(2))) unsigned int;
        uint2v r = __builtin_amdgcn_permlane16_swap(
            __float_as_uint(s), __float_as_uint(s), false, false);
        s = __uint_as_float(r.x) + __uint_as_float(r.y);
    }
#else
    s += __int_as_float(__builtin_amdgcn_ds_swizzle(__float_as_int(s), 0x401F));
#endif
#if __has_builtin(__builtin_amdgcn_permlane32_swap)
    {
        using uint2v = __attribute__((ext_vector_type(2))) unsigned int;
        uint2v r = __builtin_amdgcn_permlane32_swap(
            __float_as_uint(s), __float_as_uint(s), false, false);
        s = __uint_as_float(r.x) + __uint_as_float(r.y);
    }
#else
    s += __shfl_xor(s, 32, 64);
#endif
    return s;
}

// ---- prep (R26 version: coalesced 62-col W2 pass; og-major small prep) ----
template <int CNT>
__device__ __forceinline__ void prep_w2_cls(int d, int b, const float* __restrict__ W2,
                                            unsigned* __restrict__ pb32, int t,
                                            float (*tile)[63]) {
    const int bse  = base_of(d);
    const int col0 = 62 * b;
    const int ncol = (col0 + 62 <= NH) ? 62 : (NH - col0);   // 32 for b=16
#pragma unroll 1
    for (int e = t; e < CNT * 62; e += 256) {
        int k = e / 62, c = e - 62 * k;
        if (c < ncol) tile[k][c] = W2[(size_t)(d + 31 * k) * NH + col0 + c];
    }
    __syncthreads();
#pragma unroll 1
    for (int e = t; e < 31 * CNT; e += 256) {
        int dd = e / CNT, k = e - CNT * dd;
        int sg = bse + k;
        float lo = (d >= dd) ? tile[k][dd] : 0.0f;            // u = 2b
        float hi = 0.0f;                                       // u = 2b+1
        if (d >= dd && (col0 + dd + 31) < NH) hi = tile[k][dd + 31];
        unsigned pk = (unsigned)f2h(lo) | ((unsigned)f2h(hi) << 16);
        pb32[(size_t)((dd * 17 + b) * 256 + (sg >> 2)) * 4 + (sg & 3)] = pk;
    }
}

__global__ __launch_bounds__(256) void prep_all(const float* __restrict__ W1,
        const float* __restrict__ b1, const float* __restrict__ W2,
        const float* __restrict__ b2, const float* __restrict__ W3,
        float* __restrict__ ws) {
    __shared__ float tile[34][63];
    const int bid = blockIdx.x, t = threadIdx.x;
    unsigned* pb32 = (unsigned*)(ws + OFF_PB);
    if (bid < 527) {
        int d = bid / 17, b = bid - 17 * d;
        if (d == 0) prep_w2_cls<34>(0, b, W2, pb32, t, tile);
        else        prep_w2_cls<33>(d, b, W2, pb32, t, tile);
    } else if (bid < 591) {
        // W3s row o: coalesced read of W3[o][*], scatter-store to su.
        const int o  = bid - 527;
        const int od = (o & 31) - 1;
#pragma unroll 1
        for (int e = t; e < NH; e += 256) {       // e = og
            int dd = e % 31;
            int k  = e / 31;
            int su = (dd == 0) ? k : 33 * dd + 1 + k;
            float v = (od >= dd) ? W3[(size_t)o * NH + e] : 0.0f;
            ws[OFF_W3S + (size_t)o * NH + su] = v;
        }
    } else {
        // W1B + b1s + b2s: one thread per og; contiguous 128B W1 row/lane.
        const int og = (bid - 591) * 256 + t;
        const int dd = og % 31;
        const int k  = og / 31;
        const int su = (dd == 0) ? k : 33 * dd + 1 + k;
        ws[OFF_B1S + su] = b1[og];
        ws[OFF_B2S + su] = b2[og];
        unsigned* w1b32 = (unsigned*)(ws + OFF_W1B);
        const float4* wrow = (const float4*)(W1 + (size_t)og * NI);
        float4 r[8];
#pragma unroll
        for (int q4 = 0; q4 < 8; ++q4) r[q4] = wrow[q4];
        const float* rf = (const float*)&r[0];
#pragma unroll
        for (int jp = 0; jp < 16; ++jp) {
            float v0 = (dd >= 2 * jp)     ? rf[2 * jp]     : 0.0f;
            float v1 = (dd >= 2 * jp + 1) ? rf[2 * jp + 1] : 0.0f;
            unsigned pk = (unsigned)f2h(v0) | ((unsigned)f2h(v1) << 16);
            w1b32[(size_t)jp * 1056 + su] = pk;
        }
    }
}

// consume one f16 pair-load with dot2: g.{x,y,z,w} = k-pair for unit sg0..3;
// av.x = packed (a0[2u2],a0[2u2+1]), av.y = same for row 1.
__device__ __forceinline__ void consume_pair(uint4 g, uint2 av,
                                             float4& acc0, float4& acc1) {
    acc0.x = fdot2u(av.x, g.x, acc0.x);
    acc0.y = fdot2u(av.x, g.y, acc0.y);
    acc0.z = fdot2u(av.x, g.z, acc0.z);
    acc0.w = fdot2u(av.x, g.w, acc0.w);
    acc1.x = fdot2u(av.y, g.x, acc1.x);
    acc1.y = fdot2u(av.y, g.y, acc1.y);
    acc1.z = fdot2u(av.y, g.z, acc1.z);
    acc1.w = fdot2u(av.y, g.w, acc1.w);
}

// Phase A with NG tap-groups (group q4 covers taps 8q4..8q4+7). Called with
// ng = ceil(i/8): taps j>=i have exactly-zero weights AND xsH[j]=0, so
// skipped groups contribute exact zeros — bit-identical result. Unlike
// R21's per-group gating, each arm is flat/batched (no load serialization).
template <int NG>
__device__ __forceinline__ void phase_a(const unsigned* __restrict__ W1Bsu,
        float bz, const unsigned* __restrict__ xh0,
        const unsigned* __restrict__ xh1, float& a0, float& a1) {
    unsigned wk[4 * NG];
#pragma unroll
    for (int k = 0; k < 4 * NG; ++k) wk[k] = W1Bsu[k * 1056];
    float zA0 = bz, zA1 = 0, zA2 = 0, zA3 = 0;
    float zB0 = bz, zB1 = 0, zB2 = 0, zB3 = 0;
#pragma unroll
    for (int q4 = 0; q4 < NG; ++q4) {
        uint4 xp0 = *(const uint4*)(xh0 + 4 * q4);
        uint4 xp1 = *(const uint4*)(xh1 + 4 * q4);
        zA0 = fdot2u(xp0.x, wk[4 * q4 + 0], zA0);
        zB0 = fdot2u(xp1.x, wk[4 * q4 + 0], zB0);
        zA1 = fdot2u(xp0.y, wk[4 * q4 + 1], zA1);
        zB1 = fdot2u(xp1.y, wk[4 * q4 + 1], zB1);
        zA2 = fdot2u(xp0.z, wk[4 * q4 + 2], zA2);
        zB2 = fdot2u(xp1.z, wk[4 * q4 + 2], zB2);
        zA3 = fdot2u(xp0.w, wk[4 * q4 + 3], zA3);
        zB3 = fdot2u(xp1.w, wk[4 * q4 + 3], zB3);
    }
    a0 = fmaxf((zA0 + zA1) + (zA2 + zA3), 0.f);
    a1 = fmaxf((zB0 + zB1) + (zB2 + zB3), 0.f);
}

// FINAL (R30) = R27 verbatim — session best, 139.56us total / 71.9us scan.
// Session ledger: 166.6 -> 139.6us. Scan 99.6 -> 71.9us via (1) DPP+permlane
// wave_allsum (replaced 6-level ds_swizzle butterfly), (2) f16 v_dot2_f32_f16
// consume/PhaseA (halved the issue stream; absmax unchanged), (3) unpinned
// scheduler + truncated Phase-A arms. Refuted with counters: occupancy
// forcing (R15-17,R23), source-level pipelining (R21,R22,R24,R28), prep
// rewrites (R20,R25,R26: residual ~60us is fixed harness overhead), traffic
// cut (R29: -14% FETCH, +2.5% time). Plateau state: VALUBusy ~40%, HBM ~1%,
// bank-conflicts 0, spills 0 — no counter ceiling. The floor is the
// 31-step serial dependency chain (~5.6k cyc/step, latency double-covered
// by the co-resident block); past it requires a different factorization of
// the recurrence, not kernel tuning.
__global__ __launch_bounds__(256, 2) void made_scan(
        const float* __restrict__ inputs,
        const float* __restrict__ b3,
        const float* __restrict__ ws,
        float* __restrict__ out) {
    __shared__ float    xsS[4][2][36];  // per-wave private x, f32 (output path)
    __shared__ unsigned xsH[4][2][20];  // per-wave x as packed f16 pairs
    __shared__ unsigned a1H[4][36];     // per-wave a pairs: [u2*2]=row0, [u2*2+1]=row1
    __shared__ float part[2][4][4];
    __shared__ float b3S[64];
    __shared__ float xinS[2][NI];

    const int lane = threadIdx.x & 63;
    const int w    = threadIdx.x >> 6;
    const int pairity = ((blockIdx.x >> 8) ^ blockIdx.x) & 1;
    const int q    = w ^ (pairity * 3);
    const int gb   = q * 256;
    const int row0 = blockIdx.x * 2;

    const float* b1s = ws + OFF_B1S;
    const float* b2s = ws + OFF_B2S;
    const float* W3s = ws + OFF_W3S;
    const unsigned* W1B = (const unsigned*)(ws + OFF_W1B);
    const uint4*    PB  = (const uint4*)(ws + OFF_PB);

    float4 acc0 = ((const float4*)(b2s + gb))[lane];
    float4 acc1 = acc0;
    float J0 = 0.f, J1 = 0.f;

    if (w == 0) {
        b3S[lane] = b3[lane];
        if (lane < NI) {
            xinS[0][lane] = inputs[row0 * NI + lane];
            xinS[1][lane] = inputs[(row0 + 1) * NI + lane];
        }
    }
    {
        float* px = &xsS[w][0][0];
        for (int k = lane; k < 72; k += 64) px[k] = 0.f;
        unsigned* ph = &xsH[w][0][0];
        for (int k = lane; k < 40; k += 64) ph[k] = 0u;
    }
    __syncthreads();

    // step 0: W3 rows 0/32 fully masked -> p = (b3[0], b3[32])
    {
        float p00 = b3S[0], p01 = b3S[NI];
        float e20 = __expf(2.f * fminf(p01, 15.f));
        float ta  = (e20 - 1.f) / (e20 + 1.f);
        float es  = __expf(ta);
        float x0  = fmaf(xinS[0][0], es, p00);
        float x1  = fmaf(xinS[1][0], es, p00);
        J0 -= ta; J1 -= ta;
        if (lane == 0) {
            xsS[w][0][0] = x0; xsS[w][1][0] = x1;
            ((unsigned short*)&xsH[w][0][0])[0] = f2h(x0);
            ((unsigned short*)&xsH[w][1][0])[0] = f2h(x1);
        }
    }

#pragma unroll 1
    for (int i = 1; i < NI; ++i) {
        const int dd   = i - 1;
        const int goff = base_of(dd);
        const int cnt  = (i == 1) ? 34 : 33;
        const bool doB = (gb + 256 > goff);
        const bool doC = (gb < 33 * i + 1);

        float4 wa = make_float4(0, 0, 0, 0), wb = make_float4(0, 0, 0, 0);
        if (doC) {
            wa = ((const float4*)(W3s + (size_t)i * NH + gb))[lane];
            wb = ((const float4*)(W3s + (size_t)(NI + i) * NH + gb))[lane];
        }

        if (doB) {
            const uint4* pbase = PB + (size_t)(dd * 17) * 256 + (gb >> 2) + lane;
            uint4 G[17];
#pragma unroll
            for (int u2 = 0; u2 < 17; ++u2) G[u2] = pbase[u2 * 256];

            // Phase A (truncated, batched arms; compiler schedules freely
            // against the G loads above — no pins).
            const int su = goff + lane;
            float bz = b1s[su];
            const unsigned* xh0 = &xsH[w][0][0];
            const unsigned* xh1 = &xsH[w][1][0];
            const unsigned* W1Bsu = W1B + su;
            float a0, a1;
            const int ng = (i + 7) >> 3;           // ceil(i/8)
            if      (ng == 1) phase_a<1>(W1Bsu, bz, xh0, xh1, a0, a1);
            else if (ng == 2) phase_a<2>(W1Bsu, bz, xh0, xh1, a0, a1);
            else if (ng == 3) phase_a<3>(W1Bsu, bz, xh0, xh1, a0, a1);
            else              phase_a<4>(W1Bsu, bz, xh0, xh1, a0, a1);
            const bool ok = lane < cnt;
            a0 = ok ? a0 : 0.f;
            a1 = ok ? a1 : 0.f;
            if (lane < 36) {                 // publish packed f16 pairs
                unsigned short* ah = (unsigned short*)&a1H[w][0];
                int u2 = lane >> 1, h = lane & 1;
                ah[u2 * 4 + h]     = f2h(a0);
                ah[u2 * 4 + 2 + h] = f2h(a1);
            }

#pragma unroll
            for (int u2 = 0; u2 < 17; ++u2)
                consume_pair(G[u2], *(const uint2*)&a1H[w][2 * u2], acc0, acc1);
        }

        // Phase C (fp32 W3; zeros beyond prefix keep it exact)
        float s00 = 0, s01 = 0, s10 = 0, s11 = 0;
        if (doC) {
            float hx, hy, hz, hw;
            hx = fmaxf(acc0.x, 0.f); hy = fmaxf(acc0.y, 0.f);
            hz = fmaxf(acc0.z, 0.f); hw = fmaxf(acc0.w, 0.f);
            s00 = fmaf(wa.x, hx, fmaf(wa.y, hy, fmaf(wa.z, hz, wa.w * hw)));
            s01 = fmaf(wb.x, hx, fmaf(wb.y, hy, fmaf(wb.z, hz, wb.w * hw)));
            hx = fmaxf(acc1.x, 0.f); hy = fmaxf(acc1.y, 0.f);
            hz = fmaxf(acc1.z, 0.f); hw = fmaxf(acc1.w, 0.f);
            s10 = fmaf(wa.x, hx, fmaf(wa.y, hy, fmaf(wa.z, hz, wa.w * hw)));
            s11 = fmaf(wb.x, hx, fmaf(wb.y, hy, fmaf(wb.z, hz, wb.w * hw)));
            s00 = wave_allsum(s00); s01 = wave_allsum(s01);
            s10 = wave_allsum(s10); s11 = wave_allsum(s11);
        }
        if (lane == 0)
            *((float4*)&part[i & 1][w][0]) = make_float4(s00, s01, s10, s11);
        __syncthreads();

        // combine — replicated in every wave; x published to own-wave xs only
        const float* pb = &part[i & 1][0][0];
        float4 q0 = ((const float4*)pb)[0], q1 = ((const float4*)pb)[1];
        float4 q2 = ((const float4*)pb)[2], q3 = ((const float4*)pb)[3];
        float bi  = b3S[i];
        float bia = b3S[NI + i];
        float p00 = ((q0.x + q1.x) + (q2.x + q3.x)) + bi;
        float p01 = ((q0.y + q1.y) + (q2.y + q3.y)) + bia;
        float p10 = ((q0.z + q1.z) + (q2.z + q3.z)) + bi;
        float p11 = ((q0.w + q1.w) + (q2.w + q3.w)) + bia;
        float e20 = __expf(2.f * fminf(p01, 15.f));
        float ta0 = (e20 - 1.f) / (e20 + 1.f);
        float x0  = fmaf(xinS[0][i], __expf(ta0), p00);
        float e21 = __expf(2.f * fminf(p11, 15.f));
        float ta1 = (e21 - 1.f) / (e21 + 1.f);
        float x1  = fmaf(xinS[1][i], __expf(ta1), p10);
        J0 -= ta0; J1 -= ta1;
        if (lane == 0) {
            xsS[w][0][i] = x0; xsS[w][1][i] = x1;
            ((unsigned short*)&xsH[w][0][0])[i] = f2h(x0);
            ((unsigned short*)&xsH[w][1][0])[i] = f2h(x1);
        }
    }

    if (w == 0) {
        if (lane < NI) {
            out[row0 * NI + lane]       = xsS[0][0][lane];
            out[(row0 + 1) * NI + lane] = xsS[0][1][lane];
        }
        if (lane == 0) {
            out[NB * NI + row0]     = J0;
            out[NB * NI + row0 + 1] = J1;
        }
    }
}

extern "C" void kernel_launch(void* const* d_in, const int* in_sizes, int n_in,
                              void* d_out, int out_size, void* d_ws, size_t ws_size,
                              hipStream_t stream) {
    const float* inputs = (const float*)d_in[0];
    const float* W1     = (const float*)d_in[1];
    const float* b1     = (const float*)d_in[2];
    const float* W2     = (const float*)d_in[3];
    const float* b2     = (const float*)d_in[4];
    const float* W3     = (const float*)d_in[5];
    const float* b3     = (const float*)d_in[6];
    float* out = (float*)d_out;
    float* ws  = (float*)d_ws;

    prep_all<<<595, 256, 0, stream>>>(W1, b1, W2, b2, W3, ws);
    made_scan<<<NB / 2, 256, 0, stream>>>(inputs, b3, ws, out);
}